// Round 12
// baseline (681.504 us; speedup 1.0000x reference)
//
#include <hip/hip_runtime.h>
#include <stdint.h>

#define B_  256
#define T_  512
#define H_  128
#define NSW 6

typedef __bf16 bf16x8 __attribute__((ext_vector_type(8)));
typedef __bf16 bf2_t  __attribute__((ext_vector_type(2)));
typedef float  f32x4  __attribute__((ext_vector_type(4)));

// float -> bf16 round-to-nearest-even
__device__ __forceinline__ unsigned short f2bf(float f){
  unsigned u = __float_as_uint(f);
  unsigned r = u + 0x7FFFu + ((u >> 16) & 1u);
  return (unsigned short)(r >> 16);
}
__device__ __forceinline__ unsigned pack2(float a, float b){
  return (unsigned)f2bf(a) | ((unsigned)f2bf(b) << 16);
}

// acc += dot2(bf16x2 w, bf16x2 h)   (used only for the tiny input projection)
__device__ __forceinline__ float dot2bf(unsigned wpair, unsigned hpair, float acc){
  return __builtin_amdgcn_fdot2_f32_bf16(__builtin_bit_cast(bf2_t, wpair),
                                         __builtin_bit_cast(bf2_t, hpair), acc, false);
}

// LDS-only barrier: drains lgkmcnt but NOT vmcnt.
__device__ __forceinline__ void lds_barrier(){
  asm volatile("s_waitcnt lgkmcnt(0)\ns_barrier" ::: "memory");
}

// Pack weights into MFMA A-fragment order.
// 16-byte chunk index: (((g*6+s)*2 + hf)*16 + tile)*64 + L
//   tile = rg*4 + kc  (rg: 16-row group of this half, kc: 32-wide k chunk)
//   lane L holds A[row = hf*64 + rg*16 + (L&15)][k = kc*32 + (L>>4)*8 + 0..7]
__global__ __launch_bounds__(256) void pack_weights(const float* __restrict__ Wr,
                                                    const float* __restrict__ Wz,
                                                    const float* __restrict__ Wn,
                                                    uint4* __restrict__ dst){
  int idx = blockIdx.x * 256 + threadIdx.x;
  if (idx >= 3 * NSW * 2 * 16 * 64) return;   // 36864
  int L    = idx & 63;
  int tile = (idx >> 6) & 15;
  int hf   = (idx >> 10) & 1;
  int gs   = idx >> 11;          // g*6+s, < 18
  int s    = gs % NSW;
  int g    = gs / NSW;
  int rg   = tile >> 2;
  int kc   = tile & 3;
  int row  = hf * 64 + rg * 16 + (L & 15);
  int k0   = kc * 32 + (L >> 4) * 8;
  const float* W = (g == 0) ? Wr : (g == 1) ? Wz : Wn;
  const float* src = W + (size_t)s * (H_*H_) + (size_t)row * H_ + k0;
  uint4 o;
  o.x = pack2(src[0], src[1]);
  o.y = pack2(src[2], src[3]);
  o.z = pack2(src[4], src[5]);
  o.w = pack2(src[6], src[7]);
  dst[idx] = o;
}

// 384 threads = 6 waves. wave w: gate g = w>>1, row-half hf = w&1.
// Each wave computes its 64x128 weight block times h via 16 MFMAs (N=1 in B).
__global__ __launch_bounds__(384, 1) void gru_run(const float* __restrict__ stim,
    const int*   __restrict__ swid,  const float* __restrict__ mask,
    const float* __restrict__ Win,   const float* __restrict__ binp,
    const float* __restrict__ b_hr,  const float* __restrict__ b_hz, const float* __restrict__ b_hn,
    const float* __restrict__ Wo,    const float* __restrict__ bo,
    const uint4* __restrict__ Wpk,   float* __restrict__ out)
{
  const int b   = blockIdx.x;
  const int tid = threadIdx.x;
  const int w   = tid >> 6;
  const int L   = tid & 63;
  const int g   = w >> 1;
  const int hf  = w & 1;

  __shared__ uint4          s_stim2[T_];       // 8 KB  bf16 stim pairs
  __shared__ float          s_mask[T_];        // 2 KB
  __shared__ unsigned short s_sid[T_];         // 1 KB
  __shared__ float          s_b[3*NSW*H_];     // 9 KB  fp32 biases [g][s][i]
  __shared__ float          s_x[3*H_];         // 1.5 KB input projections
  __shared__ float          s_acc[3*H_];       // 1.5 KB matvec results
  __shared__ float          s_h[H_];           // fp32 h
  __shared__ __align__(16) unsigned s_hb[68];  // h bf16 pairs + 16B zero pad [64..67]

  // ---- init LDS ----
  for (int k = tid; k < T_; k += 384){
    const float* sp = stim + (size_t)b * T_ * 8 + (size_t)k * 8;
    uint4 o;
    o.x = pack2(sp[0], sp[1]); o.y = pack2(sp[2], sp[3]);
    o.z = pack2(sp[4], sp[5]); o.w = pack2(sp[6], sp[7]);
    s_stim2[k] = o;
    s_mask[k] = mask[(size_t)b * T_ + k];
    int ss = swid[(size_t)b * T_ + k];
    s_sid[k] = (unsigned short)(ss < 0 ? 0 : (ss > NSW - 1 ? NSW - 1 : ss));
  }
  for (int k = tid; k < 3 * NSW * H_; k += 384){
    int gg = k / (NSW * H_); int rr = k % (NSW * H_);
    const float* bp = (gg == 0) ? b_hr : (gg == 1) ? b_hz : b_hn;
    s_b[k] = bp[rr];
  }
  if (tid < H_) s_h[tid] = 0.f;
  if (tid < 68) s_hb[tid] = 0u;

  // input-projection row for output orow = tid (= g*128 + hf*64 + L)
  unsigned winp[4];
  #pragma unroll
  for (int e = 0; e < 4; ++e)
    winp[e] = pack2(Win[(size_t)tid * 8 + 2*e], Win[(size_t)tid * 8 + 2*e + 1]);
  const float binr = binp[tid];

  // logit weights: wave 2 -> logit 0, wave 3 -> logit 1
  float wo_a = 0.f, wo_b = 0.f, bo_r = 0.f;
  const int kk = (w == 3) ? 1 : 0;
  if (g == 1){
    wo_a = Wo[kk * H_ + L];
    wo_b = Wo[kk * H_ + 64 + L];
    bo_r = bo[kk];
  }

  // wave's weight base: + s*2048 per step, tile stride 64 uint4s
  const uint4* wbase = Wpk + ((size_t)g * NSW * 2 + hf) * 1024 + L;
  const bool colv = (L & 15) == 0;     // lanes holding B/D column 0
  const int  quad = L >> 4;
  float* outp = out + (size_t)b * T_ * 2;

  __syncthreads();

  int sc = __builtin_amdgcn_readfirstlane((int)s_sid[0]);
  int sn = __builtin_amdgcn_readfirstlane((int)s_sid[1]);

  #pragma unroll 1
  for (int t = 0; t < T_; ++t){
    // ---- weight loads for this step (A fragments, at-use waits) ----
    const uint4* wp = wbase + (size_t)sc * 2048;
    uint4 A[16];
    #pragma unroll
    for (int j = 0; j < 16; ++j) A[j] = wp[j * 64];

    // ---- B fragments: lane holds B[k = quad*8 + j][col = L&15], j=0..7.
    //      col-0 lanes read h[kc*32 + quad*8 .. +7] (16 B); others read the
    //      16-B zero pad at byte offset 256 -> cols 1..15 are all-zero.
    uint4 bf[4];
    #pragma unroll
    for (int kc = 0; kc < 4; ++kc){
      int off = colv ? (kc * 64 + quad * 16) : 256;   // bytes into s_hb
      bf[kc] = *reinterpret_cast<const uint4*>(reinterpret_cast<const char*>(s_hb) + off);
    }

    // ---- input projection x for output row tid ----
    uint4 sp = s_stim2[t];
    float x = binr;
    x = dot2bf(winp[0], sp.x, x);
    x = dot2bf(winp[1], sp.y, x);
    x = dot2bf(winp[2], sp.z, x);
    x = dot2bf(winp[3], sp.w, x);
    s_x[tid] = x;

    int tn2 = (t + 2 < T_) ? t + 2 : T_ - 1;
    int snl = (int)s_sid[tn2];

    // ---- 16 MFMAs: acc[rg] = sum_kc A[rg*4+kc] * B[kc] ----
    f32x4 acc[4];
    #pragma unroll
    for (int rg = 0; rg < 4; ++rg){
      acc[rg] = f32x4{0.f, 0.f, 0.f, 0.f};
      #pragma unroll
      for (int kc = 0; kc < 4; ++kc){
        bf16x8 a  = __builtin_bit_cast(bf16x8, A[rg * 4 + kc]);
        bf16x8 bb = __builtin_bit_cast(bf16x8, bf[kc]);
        acc[rg] = __builtin_amdgcn_mfma_f32_16x16x32_bf16(a, bb, acc[rg], 0, 0, 0);
      }
    }
    // D: col=L&15, row = quad*4 + reg. col-0 lanes write 4 rows each.
    if (colv){
      #pragma unroll
      for (int rg = 0; rg < 4; ++rg)
        *reinterpret_cast<f32x4*>(&s_acc[g * H_ + hf * 64 + rg * 16 + quad * 4]) = acc[rg];
    }

    lds_barrier();   // B1: s_acc + s_x visible

    if (tid < H_){
      const int i = tid;
      float hr = s_acc[i]        + s_b[0 * (NSW*H_) + sc * H_ + i];
      float hz = s_acc[H_ + i]   + s_b[1 * (NSW*H_) + sc * H_ + i];
      float hn = s_acc[2*H_ + i] + s_b[2 * (NSW*H_) + sc * H_ + i];
      float xr = s_x[i], xz = s_x[H_ + i], xn = s_x[2*H_ + i];
      float r = 1.f / (1.f + __expf(-(xr + hr)));
      float z = 1.f / (1.f + __expf(-(xz + hz)));
      float e = __expf(2.f * (xn + r * hn));       // tanh(a) = 1 - 2/(e^{2a}+1)
      float n = 1.f - 2.f / (e + 1.f);
      float hprev = s_h[i];
      float hnew  = (1.f - z) * n + z * hprev;
      float mt    = s_mask[t];
      float ho    = mt * hnew + (1.f - mt) * hprev;
      s_h[i] = ho;
      ((unsigned short*)s_hb)[i] = f2bf(ho);
    }

    lds_barrier();   // B2: h visible

    if (g == 1){
      float p = wo_a * s_h[L] + wo_b * s_h[64 + L];
      p += __shfl_down(p, 32); p += __shfl_down(p, 16); p += __shfl_down(p, 8);
      p += __shfl_down(p, 4);  p += __shfl_down(p, 2);  p += __shfl_down(p, 1);
      if (L == 0) outp[t * 2 + kk] = p + bo_r;
    }

    sc = sn;
    sn = __builtin_amdgcn_readfirstlane(snl);
  }
}

extern "C" void kernel_launch(void* const* d_in, const int* in_sizes, int n_in,
                              void* d_out, int out_size, void* d_ws, size_t ws_size,
                              hipStream_t stream) {
  const float* stim = (const float*)d_in[0];
  const int*   swid = (const int*)  d_in[1];
  const float* mask = (const float*)d_in[2];
  const float* Win  = (const float*)d_in[3];
  const float* binp = (const float*)d_in[4];
  const float* Whr  = (const float*)d_in[5];
  const float* Whz  = (const float*)d_in[6];
  const float* Whn  = (const float*)d_in[7];
  const float* bhr  = (const float*)d_in[8];
  const float* bhz  = (const float*)d_in[9];
  const float* bhn  = (const float*)d_in[10];
  const float* Wo   = (const float*)d_in[11];
  const float* bo   = (const float*)d_in[12];

  uint4* wpk = (uint4*)d_ws;   // 589824 bytes used

  pack_weights<<<144, 256, 0, stream>>>(Whr, Whz, Whn, wpk);
  gru_run<<<B_, 384, 0, stream>>>(stim, swid, mask, Win, binp,
                                  bhr, bhz, bhn, Wo, bo, wpk, (float*)d_out);
}

// Round 13
// 633.830 us; speedup vs baseline: 1.0752x; 1.0752x over previous
//
#include <hip/hip_runtime.h>
#include <stdint.h>

#define B_  256
#define T_  512
#define H_  128
#define NSW 6

typedef __bf16 bf2_t  __attribute__((ext_vector_type(2)));
typedef int    i32x4  __attribute__((ext_vector_type(4)));
typedef float  f32x4  __attribute__((ext_vector_type(4)));

// float -> bf16 round-to-nearest-even
__device__ __forceinline__ unsigned short f2bf(float f){
  unsigned u = __float_as_uint(f);
  unsigned r = u + 0x7FFFu + ((u >> 16) & 1u);
  return (unsigned short)(r >> 16);
}
__device__ __forceinline__ unsigned pack2(float a, float b){
  return (unsigned)f2bf(a) | ((unsigned)f2bf(b) << 16);
}
__device__ __forceinline__ float dot2bf(unsigned wpair, unsigned hpair, float acc){
  return __builtin_amdgcn_fdot2_f32_bf16(__builtin_bit_cast(bf2_t, wpair),
                                         __builtin_bit_cast(bf2_t, hpair), acc, false);
}
__device__ __forceinline__ void lds_barrier(){
  asm volatile("s_waitcnt lgkmcnt(0)\ns_barrier" ::: "memory");
}

// Per-row symmetric int8 quantization into MFMA A-fragment order.
// uint2 idx = ((gs*2+hf)*16 + rg*4 + kc)*64 + q*16 + r holds int8 of
//   W[gs][row = hf*64+rg*16+r][k = kc*32 + q*8 + 0..7]  (byte e = k offset e)
// scales[gs*128+row] = rowmax / (127*127)  (dequant factor incl. h scale 1/127)
__global__ __launch_bounds__(256) void pack_weights_i8(const float* __restrict__ Wr,
                                                       const float* __restrict__ Wz,
                                                       const float* __restrict__ Wn,
                                                       uint2* __restrict__ dst,
                                                       float* __restrict__ scales){
  int idx = blockIdx.x * 256 + threadIdx.x;     // (gs, row)
  if (idx >= 18 * 128) return;
  int row = idx & 127;
  int gs  = idx >> 7;
  int s = gs % NSW, g = gs / NSW;
  const float* W = (g == 0) ? Wr : (g == 1) ? Wz : Wn;
  const float* src = W + (size_t)s * (H_*H_) + (size_t)row * H_;
  float amax = 0.f;
  for (int j = 0; j < H_; ++j) amax = fmaxf(amax, fabsf(src[j]));
  amax = fmaxf(amax, 1e-20f);
  float inv = 127.f / amax;
  scales[idx] = amax / 16129.f;                 // amax / 127^2
  int hf = row >> 6, rr = row & 63, rg = rr >> 4, r = rr & 15;
  for (int kc = 0; kc < 4; ++kc){
    for (int q = 0; q < 4; ++q){
      unsigned b0 = 0, b1 = 0;
      for (int e = 0; e < 8; ++e){
        int k = kc * 32 + q * 8 + e;
        int v = (int)rintf(src[k] * inv);
        v = v > 127 ? 127 : (v < -127 ? -127 : v);
        unsigned bv = (unsigned)(v & 0xFF);
        if (e < 4) b0 |= bv << (8 * e);
        else       b1 |= bv << (8 * (e - 4));
      }
      dst[((size_t)(gs * 2 + hf) * 16 + rg * 4 + kc) * 64 + q * 16 + r] = make_uint2(b0, b1);
    }
  }
}

// 384 threads = 6 waves. wave w: gate g = w>>1, half hf = w&1 (rows hf*64..+63).
// ALL SIX switch-sets' A-fragments live in registers (6 x 16 uint2 = 192 VGPR).
// Per step: wave-uniform switch(sid) -> 16 i8 MFMAs; zero weight traffic.
__global__ __launch_bounds__(384, 2) void gru_run(const float* __restrict__ stim,
    const int*   __restrict__ swid,  const float* __restrict__ mask,
    const float* __restrict__ Win,   const float* __restrict__ binp,
    const float* __restrict__ b_hr,  const float* __restrict__ b_hz, const float* __restrict__ b_hn,
    const float* __restrict__ Wo,    const float* __restrict__ bo,
    const uint2* __restrict__ Wpk,   const float* __restrict__ Wsc,
    float* __restrict__ out)
{
  const int b   = blockIdx.x;
  const int tid = threadIdx.x;
  const int w   = tid >> 6;
  const int L   = tid & 63;
  const int g   = w >> 1;
  const int hf  = w & 1;

  __shared__ uint4          s_stim2[T_];        // 8 KB  bf16 stim pairs
  __shared__ float          s_mask[T_];         // 2 KB
  __shared__ unsigned short s_sid[T_];          // 1 KB
  __shared__ float          s_b[3*NSW*H_];      // 9 KB  fp32 biases [g][s][i]
  __shared__ float          s_scale[3*NSW*H_];  // 9 KB  dequant factors [gs][row]
  __shared__ float          s_x[3*H_];          // 1.5 KB input projections
  __shared__ float          s_acc[3*H_];        // 1.5 KB matvec results (dequantized)
  __shared__ float          s_h[H_];            // fp32 h
  __shared__ __align__(16) char s_hb8[160];     // h int8 [0,128) + zero pad [128,160)

  // ---- init LDS ----
  for (int k = tid; k < T_; k += 384){
    const float* sp = stim + (size_t)b * T_ * 8 + (size_t)k * 8;
    uint4 o;
    o.x = pack2(sp[0], sp[1]); o.y = pack2(sp[2], sp[3]);
    o.z = pack2(sp[4], sp[5]); o.w = pack2(sp[6], sp[7]);
    s_stim2[k] = o;
    s_mask[k] = mask[(size_t)b * T_ + k];
    int ss = swid[(size_t)b * T_ + k];
    s_sid[k] = (unsigned short)(ss < 0 ? 0 : (ss > NSW - 1 ? NSW - 1 : ss));
  }
  for (int k = tid; k < 3 * NSW * H_; k += 384){
    int gg = k / (NSW * H_); int rr = k % (NSW * H_);
    const float* bp = (gg == 0) ? b_hr : (gg == 1) ? b_hz : b_hn;
    s_b[k] = bp[rr];
    s_scale[k] = Wsc[k];
  }
  if (tid < H_) s_h[tid] = 0.f;
  if (tid < 40) ((int*)s_hb8)[tid] = 0;

  // input-projection row for output row tid
  unsigned winp[4];
  #pragma unroll
  for (int e = 0; e < 4; ++e)
    winp[e] = pack2(Win[(size_t)tid * 8 + 2*e], Win[(size_t)tid * 8 + 2*e + 1]);
  const float binr = binp[tid];

  float wo_a = 0.f, wo_b = 0.f, bo_r = 0.f;
  const int kk = (w == 3) ? 1 : 0;
  if (g == 1){
    wo_a = Wo[kk * H_ + L];
    wo_b = Wo[kk * H_ + 64 + L];
    bo_r = bo[kk];
  }

  // ---- preload ALL 6 switch-sets' A fragments into registers (volatile:
  //      cannot be sunk into the loop or rematerialized) ----
  uint2 Af[6][16];
  #pragma unroll
  for (int s = 0; s < 6; ++s){
    const volatile unsigned* vp =
      (const volatile unsigned*)(Wpk + ((size_t)((g * NSW + s) * 2 + hf) * 16) * 64 + L);
    #pragma unroll
    for (int j = 0; j < 16; ++j){
      Af[s][j].x = vp[2 * (j * 64)];
      Af[s][j].y = vp[2 * (j * 64) + 1];
    }
  }

  const bool colv = (L & 15) == 0;
  const int  quad = L >> 4;
  float* outp = out + (size_t)b * T_ * 2;

  __syncthreads();

#define MM(S)                                                                  \
    _Pragma("unroll")                                                          \
    for (int rg = 0; rg < 4; ++rg){                                            \
      i32x4 a = {0, 0, 0, 0};                                                  \
      a = __builtin_amdgcn_mfma_i32_16x16x32_i8(                               \
            __builtin_bit_cast(long, Af[S][rg*4+0]), bl0, a, 0, 0, 0);         \
      a = __builtin_amdgcn_mfma_i32_16x16x32_i8(                               \
            __builtin_bit_cast(long, Af[S][rg*4+1]), bl1, a, 0, 0, 0);         \
      a = __builtin_amdgcn_mfma_i32_16x16x32_i8(                               \
            __builtin_bit_cast(long, Af[S][rg*4+2]), bl2, a, 0, 0, 0);         \
      a = __builtin_amdgcn_mfma_i32_16x16x32_i8(                               \
            __builtin_bit_cast(long, Af[S][rg*4+3]), bl3, a, 0, 0, 0);         \
      accv[rg] = a;                                                            \
    }

  #pragma unroll 1
  for (int t = 0; t < T_; ++t){
    int sc = __builtin_amdgcn_readfirstlane((int)s_sid[t]);

    // B fragments: col-0 lanes read h int8 (8 B at k = kc*32+quad*8); others zero pad
    long bl0, bl1, bl2, bl3;
    {
      int o0 = colv ? (0 * 32 + quad * 8) : 128;
      int o1 = colv ? (1 * 32 + quad * 8) : 128;
      int o2 = colv ? (2 * 32 + quad * 8) : 128;
      int o3 = colv ? (3 * 32 + quad * 8) : 128;
      bl0 = *(const long*)(s_hb8 + o0);
      bl1 = *(const long*)(s_hb8 + o1);
      bl2 = *(const long*)(s_hb8 + o2);
      bl3 = *(const long*)(s_hb8 + o3);
    }

    // input projection x for output row tid
    uint4 sp = s_stim2[t];
    float x = binr;
    x = dot2bf(winp[0], sp.x, x);
    x = dot2bf(winp[1], sp.y, x);
    x = dot2bf(winp[2], sp.z, x);
    x = dot2bf(winp[3], sp.w, x);
    s_x[tid] = x;

    // matvec from register-resident weights (wave-uniform sid dispatch)
    i32x4 accv[4];
    switch (sc){
      case 0: MM(0); break;
      case 1: MM(1); break;
      case 2: MM(2); break;
      case 3: MM(3); break;
      case 4: MM(4); break;
      default: MM(5); break;
    }

    // dequant + scatter: col-0 lanes own rows rg*16 + quad*4 + 0..3
    if (colv){
      #pragma unroll
      for (int rg = 0; rg < 4; ++rg){
        int rbase = hf * 64 + rg * 16 + quad * 4;
        f32x4 scf = *reinterpret_cast<const f32x4*>(&s_scale[(g * NSW + sc) * H_ + rbase]);
        f32x4 v;
        v.x = (float)accv[rg].x * scf.x;
        v.y = (float)accv[rg].y * scf.y;
        v.z = (float)accv[rg].z * scf.z;
        v.w = (float)accv[rg].w * scf.w;
        *reinterpret_cast<f32x4*>(&s_acc[g * H_ + rbase]) = v;
      }
    }

    lds_barrier();   // B1: s_acc + s_x visible

    if (tid < H_){
      const int i = tid;
      float hr = s_acc[i]        + s_b[0 * (NSW*H_) + sc * H_ + i];
      float hz = s_acc[H_ + i]   + s_b[1 * (NSW*H_) + sc * H_ + i];
      float hn = s_acc[2*H_ + i] + s_b[2 * (NSW*H_) + sc * H_ + i];
      float xr = s_x[i], xz = s_x[H_ + i], xn = s_x[2*H_ + i];
      float r = 1.f / (1.f + __expf(-(xr + hr)));
      float z = 1.f / (1.f + __expf(-(xz + hz)));
      float e = __expf(2.f * (xn + r * hn));       // tanh(a) = 1 - 2/(e^{2a}+1)
      float n = 1.f - 2.f / (e + 1.f);
      float hprev = s_h[i];
      float hnew  = (1.f - z) * n + z * hprev;
      float mt    = s_mask[t];
      float ho    = mt * hnew + (1.f - mt) * hprev;
      s_h[i] = ho;
      int qi = (int)rintf(ho * 127.f);
      qi = qi > 127 ? 127 : (qi < -127 ? -127 : qi);
      s_hb8[i] = (char)qi;
    }

    lds_barrier();   // B2: h visible

    if (g == 1){
      float p = wo_a * s_h[L] + wo_b * s_h[64 + L];
      p += __shfl_down(p, 32); p += __shfl_down(p, 16); p += __shfl_down(p, 8);
      p += __shfl_down(p, 4);  p += __shfl_down(p, 2);  p += __shfl_down(p, 1);
      if (L == 0) outp[t * 2 + kk] = p + bo_r;
    }
  }
#undef MM
}

extern "C" void kernel_launch(void* const* d_in, const int* in_sizes, int n_in,
                              void* d_out, int out_size, void* d_ws, size_t ws_size,
                              hipStream_t stream) {
  const float* stim = (const float*)d_in[0];
  const int*   swid = (const int*)  d_in[1];
  const float* mask = (const float*)d_in[2];
  const float* Win  = (const float*)d_in[3];
  const float* binp = (const float*)d_in[4];
  const float* Whr  = (const float*)d_in[5];
  const float* Whz  = (const float*)d_in[6];
  const float* Whn  = (const float*)d_in[7];
  const float* bhr  = (const float*)d_in[8];
  const float* bhz  = (const float*)d_in[9];
  const float* bhn  = (const float*)d_in[10];
  const float* Wo   = (const float*)d_in[11];
  const float* bo   = (const float*)d_in[12];

  uint2* wpk = (uint2*)d_ws;                       // 294912 B packed int8 frags
  float* wsc = (float*)((char*)d_ws + 294912);     // 9216 B row scales

  pack_weights_i8<<<9, 256, 0, stream>>>(Whr, Whz, Whn, wpk, wsc);
  gru_run<<<B_, 384, 0, stream>>>(stim, swid, mask, Win, binp,
                                  bhr, bhz, bhn, Wo, bo, wpk, wsc, (float*)d_out);
}